// Round 4
// baseline (536.421 us; speedup 1.0000x reference)
//
#include <hip/hip_runtime.h>
#include <hip/hip_bf16.h>

typedef unsigned int u32;
typedef unsigned long long u64;
typedef unsigned short u16;
typedef __bf16 bf16_t;
typedef bf16_t bf16x8 __attribute__((ext_vector_type(8)));
typedef float f32x4 __attribute__((ext_vector_type(4)));
typedef float f32x4v __attribute__((ext_vector_type(4)));
typedef u16 u16x8 __attribute__((ext_vector_type(8)));

#define GLB __attribute__((address_space(1)))
#define LDSAS __attribute__((address_space(3)))

#define DM 2048
#define NH 16
#define DH 128
#define BB 2
#define TT 2048
#define MT (BB*TT)   // 4096

static __device__ __forceinline__ u16 f2bf(float f){
    u32 x = __builtin_bit_cast(u32, f);
    return (u16)((x + 0x7FFFu + ((x >> 16) & 1u)) >> 16);
}

static __device__ __forceinline__ f32x4 mfma16(bf16x8 a, bf16x8 b, f32x4 c){
    return __builtin_amdgcn_mfma_f32_16x16x32_bf16(a, b, c, 0, 0, 0);
}

static __device__ __forceinline__ void gload_lds16(const u16* g, u16* l){
    __builtin_amdgcn_global_load_lds((const GLB u32*)g, (LDSAS u32*)l, 16, 0, 0);
}

// ---------------------------------------------------------------------------
// fp32 -> bf16 casts for q,k,v and the 4 weights. 8 elements / thread.
// ---------------------------------------------------------------------------
__global__ __launch_bounds__(256) void cast_all(
    const float* __restrict__ q, const float* __restrict__ kin, const float* __restrict__ v,
    const float* __restrict__ wq, const float* __restrict__ wk, const float* __restrict__ wv,
    const float* __restrict__ wo,
    u16* __restrict__ qb, u16* __restrict__ kb, u16* __restrict__ vb,
    u16* __restrict__ wqb, u16* __restrict__ wkb, u16* __restrict__ wvb, u16* __restrict__ wob)
{
    const int QC = MT*DM/8;   // 1048576 chunks of 8
    const int WC = DM*DM/8;   // 524288
    int idx = blockIdx.x*256 + threadIdx.x;
    const float* src; u16* dst; int off;
    if (idx < 3*QC){
        int w = idx / QC; off = idx - w*QC;
        src = (w==0) ? q : (w==1) ? kin : v;
        dst = (w==0) ? qb : (w==1) ? kb : vb;
    } else {
        int j = idx - 3*QC; int w = j / WC; off = j - w*WC;
        src = (w==0) ? wq : (w==1) ? wk : (w==2) ? wv : wo;
        dst = (w==0) ? wqb : (w==1) ? wkb : (w==2) ? wvb : wob;
    }
    const f32x4v* s4 = (const f32x4v*)(src + (u64)off*8);
    f32x4v a = s4[0], b = s4[1];
    u16x8 r;
    r[0]=f2bf(a[0]); r[1]=f2bf(a[1]); r[2]=f2bf(a[2]); r[3]=f2bf(a[3]);
    r[4]=f2bf(b[0]); r[5]=f2bf(b[1]); r[6]=f2bf(b[2]); r[7]=f2bf(b[3]);
    *(u16x8*)(dst + (u64)off*8) = r;
}

// ---------------------------------------------------------------------------
// NT GEMM: C[M][N] = A[M][K] @ B[N][K]^T, bf16 in, M=4096 N=2048 K=2048.
// m97 structure: BM=BN=128, BK=32, 4 waves (2x2), 4x4 16x16x32 frags/wave.
// LDS staged via global_load_lds(16B) linear-dest with inverse-swizzled src;
// ds_read_b128 frags with chunk ^= (row>>1)&3 swizzle (b128 conflict floor).
// MODE 0: bf16 out. MODE 1: f32 out + bias.
// ---------------------------------------------------------------------------
template<int MODE>
__global__ __launch_bounds__(256) void gemm_bt(
    const u16* __restrict__ A0, const u16* __restrict__ B0, void* __restrict__ C0,
    const u16* __restrict__ A1, const u16* __restrict__ B1, void* __restrict__ C1,
    const u16* __restrict__ A2, const u16* __restrict__ B2, void* __restrict__ C2,
    const float* __restrict__ bias)
{
    __shared__ u16 Ash[128*32];
    __shared__ u16 Bsh[128*32];
    const u16 *A, *B; void* C;
    {
        int z = blockIdx.z;
        A = (z==0)?A0:(z==1)?A1:A2;
        B = (z==0)?B0:(z==1)?B1:B2;
        C = (z==0)?C0:(z==1)?C1:C2;
    }
    const int tid = threadIdx.x;
    const int lane = tid & 63;
    const int wave = tid >> 6;
    const int wr = wave >> 1, wc = wave & 1;
    const int g = lane >> 4, r16 = lane & 15;
    const int bm = blockIdx.y, bn = blockIdx.x;

    int srow[2], scol[2];
    #pragma unroll
    for (int rd = 0; rd < 2; rd++){
        int i = rd*256 + tid;
        int row = i >> 2;
        int c = (i & 3) ^ ((row >> 1) & 3);
        srow[rd] = row; scol[rd] = c*8;
    }
    const u16* Ag = A + (u64)(bm*128)*DM;
    const u16* Bg = B + (u64)(bn*128)*DM;

    int aoff[4], boff[4];
    #pragma unroll
    for (int mi = 0; mi < 4; mi++){
        int row = wr*64 + mi*16 + r16;
        int c = g ^ ((row >> 1) & 3);
        aoff[mi] = row*32 + c*8;
    }
    #pragma unroll
    for (int ni = 0; ni < 4; ni++){
        int row = wc*64 + ni*16 + r16;
        int c = g ^ ((row >> 1) & 3);
        boff[ni] = row*32 + c*8;
    }

    f32x4 acc[4][4] = {};

    for (int k0 = 0; k0 < DM; k0 += 32){
        #pragma unroll
        for (int rd = 0; rd < 2; rd++){
            int i = rd*256 + tid;
            gload_lds16(Ag + (u64)srow[rd]*DM + k0 + scol[rd], Ash + i*8);
            gload_lds16(Bg + (u64)srow[rd]*DM + k0 + scol[rd], Bsh + i*8);
        }
        __syncthreads();
        bf16x8 af[4], bfr[4];
        #pragma unroll
        for (int mi = 0; mi < 4; mi++) af[mi] = *(const bf16x8*)(Ash + aoff[mi]);
        #pragma unroll
        for (int ni = 0; ni < 4; ni++) bfr[ni] = *(const bf16x8*)(Bsh + boff[ni]);
        #pragma unroll
        for (int mi = 0; mi < 4; mi++)
            #pragma unroll
            for (int ni = 0; ni < 4; ni++)
                acc[mi][ni] = mfma16(af[mi], bfr[ni], acc[mi][ni]);
        __syncthreads();
    }

    #pragma unroll
    for (int mi = 0; mi < 4; mi++){
        #pragma unroll
        for (int ni = 0; ni < 4; ni++){
            int row0 = bm*128 + wr*64 + mi*16 + 4*g;
            int col  = bn*128 + wc*64 + ni*16 + r16;
            if (MODE == 0){
                u16* Cp = (u16*)C;
                #pragma unroll
                for (int rr = 0; rr < 4; rr++)
                    Cp[(u64)(row0+rr)*DM + col] = f2bf(acc[mi][ni][rr]);
            } else {
                float* Cp = (float*)C;
                float bv = bias[col];
                #pragma unroll
                for (int rr = 0; rr < 4; rr++)
                    Cp[(u64)(row0+rr)*DM + col] = acc[mi][ni][rr] + bv;
            }
        }
    }
}

// ---------------------------------------------------------------------------
// Vh [B*T][2048] -> Vt [B*H][128][T]  (Vt[bh][d][t] = Vh[b*T+t][h*128+d])
// ---------------------------------------------------------------------------
__global__ __launch_bounds__(256) void transpose_v(
    const u16* __restrict__ Vh, u16* __restrict__ Vt)
{
    __shared__ u16 tile[64*80];    // [t][d] 64x64 padded to 80
    int t0 = blockIdx.x*64, d0 = blockIdx.y*64, bh = blockIdx.z;
    int b = bh >> 4, h = bh & 15;
    int tid = threadIdx.x;
    #pragma unroll
    for (int rd = 0; rd < 2; rd++){
        int i = rd*256 + tid;
        int row = i >> 3, c = i & 7;
        u16x8 vv = *(const u16x8*)(Vh + (u64)(b*TT + t0 + row)*DM + h*DH + d0 + c*8);
        *(u16x8*)(tile + row*80 + c*8) = vv;
    }
    __syncthreads();
    #pragma unroll
    for (int rd = 0; rd < 2; rd++){
        int i = rd*256 + tid;
        int d = i >> 3, tc = (i & 7)*8;
        u16x8 vv;
        #pragma unroll
        for (int j = 0; j < 8; j++) vv[j] = tile[(tc + j)*80 + d];
        *(u16x8*)(Vt + (u64)(bh*DH + d0 + d)*TT + t0 + tc) = vv;
    }
}

// ---------------------------------------------------------------------------
// Flash attention fwd. Block = (qt, h, b): 64 q-rows, 4 waves x 16 rows.
// K tile [64][128] and Vt tile [128][64] staged swizzled (chunk ^= row&7);
// online softmax fp32 in registers; P via per-wave swizzled LDS buffer.
// ---------------------------------------------------------------------------
__global__ __launch_bounds__(256) void flash_attn(
    const u16* __restrict__ Qh, const u16* __restrict__ Kh,
    const u16* __restrict__ Vt, u16* __restrict__ Ao)
{
    __shared__ u16 Ksh[64*128];
    __shared__ u16 Vsh[128*64];
    __shared__ u16 Psh[4*16*64];
    const int qt = blockIdx.x, h = blockIdx.y, b = blockIdx.z;
    const int tid = threadIdx.x, lane = tid & 63, wave = tid >> 6;
    const int g = lane >> 4, r16 = lane & 15;
    const int bh = b*NH + h;

    bf16x8 qf[4];
    {
        const u16* qp = Qh + (u64)(b*TT + qt*64 + wave*16 + r16)*DM + h*DH + g*8;
        #pragma unroll
        for (int kc = 0; kc < 4; kc++) qf[kc] = *(const bf16x8*)(qp + kc*32);
    }
    f32x4 accO[8] = {};
    float mrow[4], lrow[4];
    #pragma unroll
    for (int r = 0; r < 4; r++){ mrow[r] = -1e30f; lrow[r] = 0.f; }
    const float scale = 0.08838834764831845f;   // 1/sqrt(128)

    u16* Pw = Psh + wave*16*64;

    for (int kv0 = 0; kv0 < TT; kv0 += 64){
        #pragma unroll
        for (int rd = 0; rd < 4; rd++){
            int i = rd*256 + tid;
            int row = i >> 4, c = (i & 15) ^ (row & 7);
            gload_lds16(Kh + (u64)(b*TT + kv0 + row)*DM + h*DH + c*8, Ksh + i*8);
        }
        #pragma unroll
        for (int rd = 0; rd < 4; rd++){
            int i = rd*256 + tid;
            int row = i >> 3, c = (i & 7) ^ (row & 7);
            gload_lds16(Vt + (u64)(bh*DH + row)*TT + kv0 + c*8, Vsh + i*8);
        }
        __syncthreads();

        // S = scale * Q K^T   (per wave: 16 q-rows x 64 kv)
        f32x4 s[4];
        #pragma unroll
        for (int nf = 0; nf < 4; nf++){
            f32x4 a = {0.f, 0.f, 0.f, 0.f};
            #pragma unroll
            for (int kc = 0; kc < 4; kc++){
                int row = nf*16 + r16;
                int c = (kc*4 + g) ^ (r16 & 7);
                bf16x8 kfr = *(const bf16x8*)(Ksh + row*128 + c*8);
                a = mfma16(qf[kc], kfr, a);
            }
            s[nf] = a * scale;
        }
        // online softmax per q-row (row = 4g + r, replicated over 16 lanes)
        #pragma unroll
        for (int r = 0; r < 4; r++){
            float mx = fmaxf(fmaxf(s[0][r], s[1][r]), fmaxf(s[2][r], s[3][r]));
            #pragma unroll
            for (int d = 1; d < 16; d <<= 1) mx = fmaxf(mx, __shfl_xor(mx, d));
            float mnew = fmaxf(mrow[r], mx);
            float alpha = __expf(mrow[r] - mnew);
            mrow[r] = mnew;
            float ls = 0.f;
            #pragma unroll
            for (int nf = 0; nf < 4; nf++){
                float p = __expf(s[nf][r] - mnew);
                s[nf][r] = p;
                ls += p;
            }
            #pragma unroll
            for (int d = 1; d < 16; d <<= 1) ls += __shfl_xor(ls, d);
            lrow[r] = lrow[r]*alpha + ls;
            #pragma unroll
            for (int nfd = 0; nfd < 8; nfd++) accO[nfd][r] *= alpha;
        }
        // P -> LDS (bf16, swizzled rows of 8x16B chunks)
        #pragma unroll
        for (int r = 0; r < 4; r++){
            int qrow = 4*g + r;
            #pragma unroll
            for (int nf = 0; nf < 4; nf++){
                int kv = nf*16 + r16;
                int c = (kv >> 3) ^ (qrow & 7);
                Pw[qrow*64 + c*8 + (kv & 7)] = f2bf(s[nf][r]);
            }
        }
        // O += P @ V
        #pragma unroll
        for (int kvc = 0; kvc < 2; kvc++){
            int cpa = (kvc*4 + g) ^ (r16 & 7);
            bf16x8 pa = *(const bf16x8*)(Pw + r16*64 + cpa*8);
            #pragma unroll
            for (int nfd = 0; nfd < 8; nfd++){
                int rowv = nfd*16 + r16;
                int cv = (kvc*4 + g) ^ (r16 & 7);
                bf16x8 vfr = *(const bf16x8*)(Vsh + rowv*64 + cv*8);
                accO[nfd] = mfma16(pa, vfr, accO[nfd]);
            }
        }
        __syncthreads();
    }

    #pragma unroll
    for (int nfd = 0; nfd < 8; nfd++){
        #pragma unroll
        for (int r = 0; r < 4; r++){
            int row = b*TT + qt*64 + wave*16 + 4*g + r;
            int col = h*DH + nfd*16 + r16;
            float o = accO[nfd][r] / lrow[r];
            Ao[(u64)row*DM + col] = f2bf(o);
        }
    }
}

// ---------------------------------------------------------------------------
extern "C" void kernel_launch(void* const* d_in, const int* in_sizes, int n_in,
                              void* d_out, int out_size, void* d_ws, size_t ws_size,
                              hipStream_t stream)
{
    const float* q  = (const float*)d_in[0];
    const float* k  = (const float*)d_in[1];
    const float* v  = (const float*)d_in[2];
    const float* wq = (const float*)d_in[3];
    const float* wk = (const float*)d_in[4];
    const float* wv = (const float*)d_in[5];
    const float* wo = (const float*)d_in[6];
    const float* bo = (const float*)d_in[7];
    float* out = (float*)d_out;

    const u64 SZQ = (u64)MT*DM;      // 8,388,608 elems
    const u64 SZW = (u64)DM*DM;      // 4,194,304 elems
    u16* ws  = (u16*)d_ws;
    u16* qb  = ws;                   // dead after projections -> reused as vt
    u16* kb  = ws + SZQ;             // dead after projections
    u16* vb  = ws + 2*SZQ;           // dead after projections -> reused as ao
    u16* wqb = ws + 3*SZQ;
    u16* wkb = wqb + SZW;
    u16* wvb = wqb + 2*SZW;
    u16* wob = wqb + 3*SZW;          // wqb..wob occupy 2*SZQ total
    u16* qh  = ws + 5*SZQ;
    u16* kh  = ws + 6*SZQ;
    u16* vh  = ws + 7*SZQ;
    u16* vt  = qb;                   // alias: qb dead after projections
    u16* ao  = vb;                   // alias: vb dead after projections
    // total footprint: 8*SZQ u16 = 134.2 MB

    cast_all<<<dim3(20480), dim3(256), 0, stream>>>(
        q, k, v, wq, wk, wv, wo, qb, kb, vb, wqb, wkb, wvb, wob);

    gemm_bt<0><<<dim3(16, 32, 3), dim3(256), 0, stream>>>(
        qb, wqb, qh, kb, wkb, kh, vb, wvb, vh, nullptr);

    transpose_v<<<dim3(32, 2, 32), dim3(256), 0, stream>>>(vh, vt);

    flash_attn<<<dim3(32, 16, 2), dim3(256), 0, stream>>>(qh, kh, vt, ao);

    gemm_bt<1><<<dim3(16, 32, 1), dim3(256), 0, stream>>>(
        ao, wob, (void*)out, ao, wob, (void*)out, ao, wob, (void*)out, bo);
}

// Round 5
// 441.696 us; speedup vs baseline: 1.2145x; 1.2145x over previous
//
#include <hip/hip_runtime.h>
#include <hip/hip_bf16.h>

typedef unsigned int u32;
typedef unsigned long long u64;
typedef unsigned short u16;
typedef __bf16 bf16_t;
typedef bf16_t bf16x8 __attribute__((ext_vector_type(8)));
typedef float f32x4 __attribute__((ext_vector_type(4)));
typedef float f32x16 __attribute__((ext_vector_type(16)));
typedef float f32x4v __attribute__((ext_vector_type(4)));
typedef u16 u16x8 __attribute__((ext_vector_type(8)));
typedef u32 u32x4 __attribute__((ext_vector_type(4)));

#define GLB __attribute__((address_space(1)))
#define LDSAS __attribute__((address_space(3)))

#define DM 2048
#define NH 16
#define DH 128
#define BB 2
#define TT 2048
#define MT (BB*TT)   // 4096

static __device__ __forceinline__ u16 f2bf(float f){
    u32 x = __builtin_bit_cast(u32, f);
    return (u16)((x + 0x7FFFu + ((x >> 16) & 1u)) >> 16);
}

static __device__ __forceinline__ f32x4 mfma16(bf16x8 a, bf16x8 b, f32x4 c){
    return __builtin_amdgcn_mfma_f32_16x16x32_bf16(a, b, c, 0, 0, 0);
}

static __device__ __forceinline__ f32x16 mfma32(bf16x8 a, bf16x8 b, f32x16 c){
    return __builtin_amdgcn_mfma_f32_32x32x16_bf16(a, b, c, 0, 0, 0);
}

static __device__ __forceinline__ u32 cvtpk(float lo, float hi){
    u32 r; asm("v_cvt_pk_bf16_f32 %0, %1, %2" : "=v"(r) : "v"(lo), "v"(hi)); return r;
}

static __device__ __forceinline__ void gload_lds16(const u16* g, u16* l){
    __builtin_amdgcn_global_load_lds((const GLB u32*)g, (LDSAS u32*)l, 16, 0, 0);
}

// ---------------------------------------------------------------------------
// fp32 -> bf16 casts for q,k,v and the 4 weights. 8 elements / thread.
// ---------------------------------------------------------------------------
__global__ __launch_bounds__(256) void cast_all(
    const float* __restrict__ q, const float* __restrict__ kin, const float* __restrict__ v,
    const float* __restrict__ wq, const float* __restrict__ wk, const float* __restrict__ wv,
    const float* __restrict__ wo,
    u16* __restrict__ qb, u16* __restrict__ kb, u16* __restrict__ vb,
    u16* __restrict__ wqb, u16* __restrict__ wkb, u16* __restrict__ wvb, u16* __restrict__ wob)
{
    const int QC = MT*DM/8;   // 1048576 chunks of 8
    const int WC = DM*DM/8;   // 524288
    int idx = blockIdx.x*256 + threadIdx.x;
    const float* src; u16* dst; int off;
    if (idx < 3*QC){
        int w = idx / QC; off = idx - w*QC;
        src = (w==0) ? q : (w==1) ? kin : v;
        dst = (w==0) ? qb : (w==1) ? kb : vb;
    } else {
        int j = idx - 3*QC; int w = j / WC; off = j - w*WC;
        src = (w==0) ? wq : (w==1) ? wk : (w==2) ? wv : wo;
        dst = (w==0) ? wqb : (w==1) ? wkb : (w==2) ? wvb : wob;
    }
    const f32x4v* s4 = (const f32x4v*)(src + (u64)off*8);
    f32x4v a = s4[0], b = s4[1];
    u16x8 r;
    r[0]=f2bf(a[0]); r[1]=f2bf(a[1]); r[2]=f2bf(a[2]); r[3]=f2bf(a[3]);
    r[4]=f2bf(b[0]); r[5]=f2bf(b[1]); r[6]=f2bf(b[2]); r[7]=f2bf(b[3]);
    *(u16x8*)(dst + (u64)off*8) = r;
}

// ---------------------------------------------------------------------------
// NT GEMM: C[M][N] = A[M][K] @ B[N][K]^T, bf16 in.  (m97 structure, 128^2)
// MODE 0: bf16 out. MODE 1: f32 out + bias.
// ---------------------------------------------------------------------------
template<int MODE>
__global__ __launch_bounds__(256) void gemm_bt(
    const u16* __restrict__ A0, const u16* __restrict__ B0, void* __restrict__ C0,
    const u16* __restrict__ A1, const u16* __restrict__ B1, void* __restrict__ C1,
    const u16* __restrict__ A2, const u16* __restrict__ B2, void* __restrict__ C2,
    const float* __restrict__ bias)
{
    __shared__ u16 Ash[128*32];
    __shared__ u16 Bsh[128*32];
    const u16 *A, *B; void* C;
    {
        int z = blockIdx.z;
        A = (z==0)?A0:(z==1)?A1:A2;
        B = (z==0)?B0:(z==1)?B1:B2;
        C = (z==0)?C0:(z==1)?C1:C2;
    }
    const int tid = threadIdx.x;
    const int lane = tid & 63;
    const int wave = tid >> 6;
    const int wr = wave >> 1, wc = wave & 1;
    const int g = lane >> 4, r16 = lane & 15;
    const int bm = blockIdx.y, bn = blockIdx.x;

    int srow[2], scol[2];
    #pragma unroll
    for (int rd = 0; rd < 2; rd++){
        int i = rd*256 + tid;
        int row = i >> 2;
        int c = (i & 3) ^ ((row >> 1) & 3);
        srow[rd] = row; scol[rd] = c*8;
    }
    const u16* Ag = A + (u64)(bm*128)*DM;
    const u16* Bg = B + (u64)(bn*128)*DM;

    int aoff[4], boff[4];
    #pragma unroll
    for (int mi = 0; mi < 4; mi++){
        int row = wr*64 + mi*16 + r16;
        int c = g ^ ((row >> 1) & 3);
        aoff[mi] = row*32 + c*8;
    }
    #pragma unroll
    for (int ni = 0; ni < 4; ni++){
        int row = wc*64 + ni*16 + r16;
        int c = g ^ ((row >> 1) & 3);
        boff[ni] = row*32 + c*8;
    }

    f32x4 acc[4][4] = {};

    for (int k0 = 0; k0 < DM; k0 += 32){
        #pragma unroll
        for (int rd = 0; rd < 2; rd++){
            int i = rd*256 + tid;
            gload_lds16(Ag + (u64)srow[rd]*DM + k0 + scol[rd], Ash + i*8);
            gload_lds16(Bg + (u64)srow[rd]*DM + k0 + scol[rd], Bsh + i*8);
        }
        __syncthreads();
        bf16x8 af[4], bfr[4];
        #pragma unroll
        for (int mi = 0; mi < 4; mi++) af[mi] = *(const bf16x8*)(Ash + aoff[mi]);
        #pragma unroll
        for (int ni = 0; ni < 4; ni++) bfr[ni] = *(const bf16x8*)(Bsh + boff[ni]);
        #pragma unroll
        for (int mi = 0; mi < 4; mi++)
            #pragma unroll
            for (int ni = 0; ni < 4; ni++)
                acc[mi][ni] = mfma16(af[mi], bfr[ni], acc[mi][ni]);
        __syncthreads();
    }

    #pragma unroll
    for (int mi = 0; mi < 4; mi++){
        #pragma unroll
        for (int ni = 0; ni < 4; ni++){
            int row0 = bm*128 + wr*64 + mi*16 + 4*g;
            int col  = bn*128 + wc*64 + ni*16 + r16;
            if (MODE == 0){
                u16* Cp = (u16*)C;
                #pragma unroll
                for (int rr = 0; rr < 4; rr++)
                    Cp[(u64)(row0+rr)*DM + col] = f2bf(acc[mi][ni][rr]);
            } else {
                float* Cp = (float*)C;
                float bv = bias[col];
                #pragma unroll
                for (int rr = 0; rr < 4; rr++)
                    Cp[(u64)(row0+rr)*DM + col] = acc[mi][ni][rr] + bv;
            }
        }
    }
}

// ---------------------------------------------------------------------------
// Vh [B*T][2048] -> Vt [B*H][128][T]  (Vt[bh][d][t] = Vh[b*T+t][h*128+d])
// ---------------------------------------------------------------------------
__global__ __launch_bounds__(256) void transpose_v(
    const u16* __restrict__ Vh, u16* __restrict__ Vt)
{
    __shared__ u16 tile[64*80];    // [t][d] 64x64 padded to 80
    int t0 = blockIdx.x*64, d0 = blockIdx.y*64, bh = blockIdx.z;
    int b = bh >> 4, h = bh & 15;
    int tid = threadIdx.x;
    #pragma unroll
    for (int rd = 0; rd < 2; rd++){
        int i = rd*256 + tid;
        int row = i >> 3, c = i & 7;
        u16x8 vv = *(const u16x8*)(Vh + (u64)(b*TT + t0 + row)*DM + h*DH + d0 + c*8);
        *(u16x8*)(tile + row*80 + c*8) = vv;
    }
    __syncthreads();
    #pragma unroll
    for (int rd = 0; rd < 2; rd++){
        int i = rd*256 + tid;
        int d = i >> 3, tc = (i & 7)*8;
        u16x8 vv;
        #pragma unroll
        for (int j = 0; j < 8; j++) vv[j] = tile[(tc + j)*80 + d];
        *(u16x8*)(Vt + (u64)(bh*DH + d0 + d)*TT + t0 + tc) = vv;
    }
}

// ---------------------------------------------------------------------------
// Flash attention fwd, 8-warp 32x32 swapped-QK^T structure (per guide §B).
// Block = 256 q-rows (8 waves x 32), KVBLK=64, K/V LDS double-buffered.
// S^T = mfma32(K, Q): lane owns P-column for q=lane&31, kv=crow(r,hi).
// Softmax: lane-local + one shfl_xor(32). P->A-frag: cvt_pk + permlane32_swap
// (T12). alpha/1/l row-redistribution via per-wave 32-float LDS broadcast.
// ---------------------------------------------------------------------------
static __device__ __forceinline__ void stage_kv(
    const u16* __restrict__ Kbase, const u16* __restrict__ Vbase,
    u16* ksh, u16* vsh, int tid)
{
    // K tile [64 kv][128 d]: 1024 16B chunks, chunk col ^= (row&7)
    #pragma unroll
    for (int rd = 0; rd < 2; rd++){
        int ci = rd*512 + tid;
        int row = ci >> 4, ch = (ci & 15) ^ (row & 7);
        gload_lds16(Kbase + (u64)row*DM + ch*8, ksh + ci*8);
    }
    // V tile [128 d][64 kv]: 1024 16B chunks, chunk col ^= (row&7)
    #pragma unroll
    for (int rd = 0; rd < 2; rd++){
        int ci = rd*512 + tid;
        int row = ci >> 3, ch = (ci & 7) ^ (row & 7);
        gload_lds16(Vbase + (u64)row*TT + ch*8, vsh + ci*8);
    }
}

__global__ __launch_bounds__(512, 2) void flash_attn2(
    const u16* __restrict__ Qh, const u16* __restrict__ Kh,
    const u16* __restrict__ Vt, u16* __restrict__ Ao)
{
    __shared__ __align__(16) u16 Ksh[2][64*128];
    __shared__ __align__(16) u16 Vsh[2][128*64];
    __shared__ __align__(16) float asc[8][32];

    // XCD swizzle: all 8 q-tiles of one (b,h) share an XCD (4 heads/XCD L2)
    const int f = blockIdx.x + 8*(blockIdx.y + 16*blockIdx.z);
    const int qt = f >> 5, bhl = f & 31;
    const int b = bhl >> 4, h = bhl & 15;
    const int bh = b*NH + h;

    const int tid = threadIdx.x, lane = tid & 63, wave = tid >> 6;
    const int l31 = lane & 31, hi = lane >> 5, l7 = lane & 7;
    const float scale = 0.08838834764831845f;   // 1/sqrt(128)

    // Q fragments: B-operand, col=q=l31, k=d=16c+8hi+j  (8 chunks over D=128)
    bf16x8 qf[8];
    {
        const u16* qp = Qh + (u64)(b*TT + qt*256 + wave*32 + l31)*DM + h*DH + hi*8;
        #pragma unroll
        for (int c = 0; c < 8; c++) qf[c] = *(const bf16x8*)(qp + c*16);
    }

    const u16* Kb = Kh + (u64)(b*TT)*DM + h*DH;
    const u16* Vb = Vt + (u64)bh*DH*TT;

    f32x16 accO[4] = {};          // O^T tiles: col=d=32dt+l31, row q=crow(r,hi)
    float m_ = -1e30f, l_ = 0.f;  // for q = l31 (both hi-halves agree)

    stage_kv(Kb, Vb, Ksh[0], Vsh[0], tid);
    __syncthreads();

    for (int it = 0; it < TT/64; it++){
        const int cur = it & 1;
        if (it < TT/64 - 1)
            stage_kv(Kb + (u64)(it+1)*64*DM, Vb + (it+1)*64,
                     Ksh[cur^1], Vsh[cur^1], tid);

        // S^T = K @ Q^T  (two 32-kv tiles)
        f32x16 s0 = {}, s1 = {};
        #pragma unroll
        for (int c = 0; c < 8; c++){
            int ch = (2*c + hi) ^ l7;
            bf16x8 k0 = *(const bf16x8*)(Ksh[cur] + l31*128 + ch*8);
            bf16x8 k1 = *(const bf16x8*)(Ksh[cur] + (32 + l31)*128 + ch*8);
            s0 = mfma32(k0, qf[c], s0);
            s1 = mfma32(k1, qf[c], s1);
        }

        // online softmax for q=l31 over this tile's 64 kv
        float pe[32];
        #pragma unroll
        for (int r = 0; r < 16; r++){ pe[r] = s0[r]*scale; pe[16+r] = s1[r]*scale; }
        float mx = pe[0];
        #pragma unroll
        for (int i = 1; i < 32; i++) mx = fmaxf(mx, pe[i]);
        mx = fmaxf(mx, __shfl_xor(mx, 32));
        float mnew = fmaxf(m_, mx);
        float alpha = __expf(m_ - mnew);
        m_ = mnew;
        float ls = 0.f;
        #pragma unroll
        for (int i = 0; i < 32; i++){ pe[i] = __expf(pe[i] - mnew); ls += pe[i]; }
        ls += __shfl_xor(ls, 32);
        l_ = l_*alpha + ls;

        // redistribute alpha[q] to O rows q=crow(r,hi) via LDS broadcast
        if (lane < 32) asc[wave][l31] = alpha;
        f32x4 av[4];
        #pragma unroll
        for (int j = 0; j < 4; j++) av[j] = *(const f32x4*)&asc[wave][8*j + 4*hi];
        #pragma unroll
        for (int dt = 0; dt < 4; dt++)
            #pragma unroll
            for (int r = 0; r < 16; r++)
                accO[dt][r] *= av[r>>2][r&3];

        // T12: P -> A-fragments in-register (16 cvt_pk + 8 permlane32_swap)
        bf16x8 pa[4];
        #pragma unroll
        for (int c = 0; c < 4; c++){
            u32 a0 = cvtpk(pe[8*c+0], pe[8*c+1]);
            u32 b0 = cvtpk(pe[8*c+4], pe[8*c+5]);
            u32 a1 = cvtpk(pe[8*c+2], pe[8*c+3]);
            u32 b1 = cvtpk(pe[8*c+6], pe[8*c+7]);
            asm volatile("v_permlane32_swap_b32 %0, %1" : "+v"(a0), "+v"(b0));
            asm volatile("v_permlane32_swap_b32 %0, %1" : "+v"(a1), "+v"(b1));
            u32x4 w = {a0, a1, b0, b1};
            pa[c] = __builtin_bit_cast(bf16x8, w);
        }

        // O^T += (P @ V)^T : A=P (row q, k=kv), B=V^T-frag (col d, k=kv)
        #pragma unroll
        for (int dt = 0; dt < 4; dt++){
            #pragma unroll
            for (int c = 0; c < 4; c++){
                int ch = (2*c + hi) ^ l7;
                bf16x8 vf = *(const bf16x8*)(Vsh[cur] + (32*dt + l31)*64 + ch*8);
                accO[dt] = mfma32(pa[c], vf, accO[dt]);
            }
        }
        __syncthreads();
    }

    // epilogue: O /= l  (1/l redistributed like alpha), write bf16
    float linv = 1.f / l_;
    if (lane < 32) asc[wave][l31] = linv;
    f32x4 lv[4];
    #pragma unroll
    for (int j = 0; j < 4; j++) lv[j] = *(const f32x4*)&asc[wave][8*j + 4*hi];
    #pragma unroll
    for (int dt = 0; dt < 4; dt++){
        #pragma unroll
        for (int r = 0; r < 16; r++){
            int qrow = (r&3) + 8*(r>>2) + 4*hi;
            int grow = b*TT + qt*256 + wave*32 + qrow;
            int gcol = h*DH + 32*dt + l31;
            Ao[(u64)grow*DM + gcol] = f2bf(accO[dt][r] * lv[r>>2][r&3]);
        }
    }
}

// ---------------------------------------------------------------------------
extern "C" void kernel_launch(void* const* d_in, const int* in_sizes, int n_in,
                              void* d_out, int out_size, void* d_ws, size_t ws_size,
                              hipStream_t stream)
{
    const float* q  = (const float*)d_in[0];
    const float* k  = (const float*)d_in[1];
    const float* v  = (const float*)d_in[2];
    const float* wq = (const float*)d_in[3];
    const float* wk = (const float*)d_in[4];
    const float* wv = (const float*)d_in[5];
    const float* wo = (const float*)d_in[6];
    const float* bo = (const float*)d_in[7];
    float* out = (float*)d_out;

    const u64 SZQ = (u64)MT*DM;      // 8,388,608 elems
    const u64 SZW = (u64)DM*DM;      // 4,194,304 elems
    u16* ws  = (u16*)d_ws;
    u16* qb  = ws;                   // dead after projections -> reused as vt
    u16* kb  = ws + SZQ;             // dead after projections
    u16* vb  = ws + 2*SZQ;           // dead after projections -> reused as ao
    u16* wqb = ws + 3*SZQ;
    u16* wkb = wqb + SZW;
    u16* wvb = wqb + 2*SZW;
    u16* wob = wqb + 3*SZW;          // wqb..wob occupy 2*SZQ total
    u16* qh  = ws + 5*SZQ;
    u16* kh  = ws + 6*SZQ;
    u16* vh  = ws + 7*SZQ;
    u16* vt  = qb;                   // alias: qb dead after projections
    u16* ao  = vb;                   // alias: vb dead after projections
    // total footprint: 8*SZQ u16 = 134.2 MB

    cast_all<<<dim3(20480), dim3(256), 0, stream>>>(
        q, k, v, wq, wk, wv, wo, qb, kb, vb, wqb, wkb, wvb, wob);

    gemm_bt<0><<<dim3(16, 32, 3), dim3(256), 0, stream>>>(
        qb, wqb, qh, kb, wkb, kh, vb, wvb, vh, nullptr);

    transpose_v<<<dim3(32, 2, 32), dim3(256), 0, stream>>>(vh, vt);

    flash_attn2<<<dim3(8, 16, 2), dim3(512), 0, stream>>>(qh, kh, vt, ao);

    gemm_bt<1><<<dim3(16, 32, 1), dim3(256), 0, stream>>>(
        ao, wob, (void*)out, ao, wob, (void*)out, ao, wob, (void*)out, bo);
}

// Round 7
// 435.316 us; speedup vs baseline: 1.2323x; 1.0147x over previous
//
#include <hip/hip_runtime.h>
#include <hip/hip_bf16.h>

typedef unsigned int u32;
typedef unsigned long long u64;
typedef unsigned short u16;
typedef __bf16 bf16_t;
typedef bf16_t bf16x8 __attribute__((ext_vector_type(8)));
typedef float f32x4 __attribute__((ext_vector_type(4)));
typedef float f32x16 __attribute__((ext_vector_type(16)));
typedef float f32x4v __attribute__((ext_vector_type(4)));
typedef u16 u16x8 __attribute__((ext_vector_type(8)));
typedef u32 u32x4 __attribute__((ext_vector_type(4)));

#define GLB __attribute__((address_space(1)))
#define LDSAS __attribute__((address_space(3)))

#define DM 2048
#define NH 16
#define DH 128
#define BB 2
#define TT 2048
#define MT (BB*TT)   // 4096

static __device__ __forceinline__ u16 f2bf(float f){
    u32 x = __builtin_bit_cast(u32, f);
    return (u16)((x + 0x7FFFu + ((x >> 16) & 1u)) >> 16);
}

static __device__ __forceinline__ f32x4 mfma16(bf16x8 a, bf16x8 b, f32x4 c){
    return __builtin_amdgcn_mfma_f32_16x16x32_bf16(a, b, c, 0, 0, 0);
}

static __device__ __forceinline__ f32x16 mfma32(bf16x8 a, bf16x8 b, f32x16 c){
    return __builtin_amdgcn_mfma_f32_32x32x16_bf16(a, b, c, 0, 0, 0);
}

static __device__ __forceinline__ u32 cvtpk(float lo, float hi){
    u32 r; asm("v_cvt_pk_bf16_f32 %0, %1, %2" : "=v"(r) : "v"(lo), "v"(hi)); return r;
}

static __device__ __forceinline__ void gload_lds16(const u16* g, u16* l){
    __builtin_amdgcn_global_load_lds((const GLB u32*)g, (LDSAS u32*)l, 16, 0, 0);
}

// ---------------------------------------------------------------------------
// fp32 -> bf16 casts for q,k,v and the 4 weights. 8 elements / thread.
// ---------------------------------------------------------------------------
__global__ __launch_bounds__(256) void cast_all(
    const float* __restrict__ q, const float* __restrict__ kin, const float* __restrict__ v,
    const float* __restrict__ wq, const float* __restrict__ wk, const float* __restrict__ wv,
    const float* __restrict__ wo,
    u16* __restrict__ qb, u16* __restrict__ kb, u16* __restrict__ vb,
    u16* __restrict__ wqb, u16* __restrict__ wkb, u16* __restrict__ wvb, u16* __restrict__ wob)
{
    const int QC = MT*DM/8;   // 1048576 chunks of 8 (pow2 -> div is shift)
    const int WC = DM*DM/8;   // 524288
    int idx = blockIdx.x*256 + threadIdx.x;
    const float* src; u16* dst; int off;
    if (idx < 3*QC){
        int w = idx / QC; off = idx - w*QC;
        src = (w==0) ? q : (w==1) ? kin : v;
        dst = (w==0) ? qb : (w==1) ? kb : vb;
    } else {
        int j = idx - 3*QC; int w = j / WC; off = j - w*WC;
        src = (w==0) ? wq : (w==1) ? wk : (w==2) ? wv : wo;
        dst = (w==0) ? wqb : (w==1) ? wkb : (w==2) ? wvb : wob;
    }
    const f32x4v* s4 = (const f32x4v*)(src + (u64)off*8);
    f32x4v a = s4[0], b = s4[1];
    u16x8 r;
    r[0]=f2bf(a[0]); r[1]=f2bf(a[1]); r[2]=f2bf(a[2]); r[3]=f2bf(a[3]);
    r[4]=f2bf(b[0]); r[5]=f2bf(b[1]); r[6]=f2bf(b[2]); r[7]=f2bf(b[3]);
    *(u16x8*)(dst + (u64)off*8) = r;
}

// ---------------------------------------------------------------------------
// Phase-interleaved NT GEMM: C[M][N] = A[M][K] @ B[N][K]^T, bf16 in.
// BM=256 BN=128 BK=64, 8 waves (4M x 2N, 64x64/wave), 512 threads.
// Triple-buffered LDS (3 x 48KB), distance-2 prefetch via global_load_lds,
// counted vmcnt(6) once per K-tile (never drains to 0 in steady state),
// 4 quadrant-phases per K-tile: {8 ds_read_b128 | stage | barrier |
// setprio(1) 8xMFMA setprio(0) | barrier}. XOR chunk swizzle (0-conflict,
// verified R5). Race-free by construction: stage target buffer's reads
// finished one full K-tile group earlier.
// MODE 0: bf16 out. MODE 1: f32 out + bias.
// ---------------------------------------------------------------------------
template<int MODE>
__global__ __launch_bounds__(512, 2) void gemm8p(
    const u16* __restrict__ A0, const u16* __restrict__ B0, void* __restrict__ C0,
    const u16* __restrict__ A1, const u16* __restrict__ B1, void* __restrict__ C1,
    const u16* __restrict__ A2, const u16* __restrict__ B2, void* __restrict__ C2,
    const float* __restrict__ bias)
{
    // per buffer: A 256x64 (16384 elems) + B 128x64 (8192 elems) = 24576
    __shared__ __align__(16) u16 lds[3*24576];

    const u16 *A, *B; void* C;
    {
        int z = blockIdx.z;
        A = (z==0)?A0:(z==1)?A1:A2;
        B = (z==0)?B0:(z==1)?B1:B2;
        C = (z==0)?C0:(z==1)?C1:C2;
    }
    const int tid = threadIdx.x;
    const int lane = tid & 63;
    const int wave = tid >> 6;
    const int wm = wave >> 1, wn = wave & 1;
    const int g = lane >> 4, r16 = lane & 15;
    const int bm = blockIdx.y, bn = blockIdx.x;

    const u16* Ag = A + (u64)(bm*256)*DM;
    const u16* Bg = B + (u64)(bn*128)*DM;

    // staging: chunk = 512thr x 16B = 64 rows; row = c*64 + (tid>>3)
    const int srow8 = (tid >> 3) & 7;            // row & 7 (c*64 doesn't affect)
    const int sch   = (tid & 7) ^ srow8;         // inverse-swizzled source chunk
    const u16* Asrc = Ag + (u64)(tid >> 3)*DM + sch*8;
    const u16* Bsrc = Bg + (u64)(tid >> 3)*DM + sch*8;

    #define STAGE_A(buf, t2, c) gload_lds16(Asrc + (u64)(c)*64*DM + (t2)*64, (buf) + (c)*4096 + tid*8)
    #define STAGE_B(buf, t2, c) gload_lds16(Bsrc + (u64)(c)*64*DM + (t2)*64, (buf) + 16384 + (c)*4096 + tid*8)

    // ds_read fragment offsets (row&7 == r16&7 since wm*64, mi*16 are mult of 8)
    int aoff[4][2], boff[4][2];
    #pragma unroll
    for (int mi = 0; mi < 4; mi++)
        #pragma unroll
        for (int kk = 0; kk < 2; kk++){
            int row = wm*64 + mi*16 + r16;
            aoff[mi][kk] = row*64 + (((4*kk + g) ^ (r16 & 7))*8);
        }
    #pragma unroll
    for (int ni = 0; ni < 4; ni++)
        #pragma unroll
        for (int kk = 0; kk < 2; kk++){
            int row = wn*64 + ni*16 + r16;
            boff[ni][kk] = 16384 + row*64 + (((4*kk + g) ^ (r16 & 7))*8);
        }

    f32x4 acc[4][4] = {};
    const int NT = DM/64;   // 32 K-tiles

    // prologue: stage tiles 0 (buf0) and 1 (buf1); drain to 6 (tile0 landed)
    #pragma unroll
    for (int c = 0; c < 4; c++) STAGE_A(lds, 0, c);
    #pragma unroll
    for (int c = 0; c < 2; c++) STAGE_B(lds, 0, c);
    #pragma unroll
    for (int c = 0; c < 4; c++) STAGE_A(lds + 24576, 1, c);
    #pragma unroll
    for (int c = 0; c < 2; c++) STAGE_B(lds + 24576, 1, c);
    asm volatile("s_waitcnt vmcnt(6)" ::: "memory");
    __builtin_amdgcn_s_barrier();
    __builtin_amdgcn_sched_barrier(0);

    int cb = 0;
    for (int t = 0; t < NT; ++t){
        const u16* bufc = lds + cb*24576;
        int sb = cb + 2; if (sb >= 3) sb -= 3;
        u16* bufs = lds + sb*24576;
        const bool st = (t + 2) < NT;

        #pragma unroll
        for (int q = 0; q < 4; ++q){
            const int qm = q >> 1, qn = q & 1;
            bf16x8 af[2][2], bff[2][2];
            #pragma unroll
            for (int i = 0; i < 2; i++)
                #pragma unroll
                for (int kk = 0; kk < 2; kk++){
                    af[i][kk]  = *(const bf16x8*)(bufc + aoff[2*qm + i][kk]);
                    bff[i][kk] = *(const bf16x8*)(bufc + boff[2*qn + i][kk]);
                }
            if (st){
                if (q == 0){ STAGE_A(bufs, t+2, 0); STAGE_A(bufs, t+2, 1); }
                else if (q == 1){ STAGE_A(bufs, t+2, 2); STAGE_A(bufs, t+2, 3); }
                else if (q == 2){ STAGE_B(bufs, t+2, 0); }
                else            { STAGE_B(bufs, t+2, 1); }
            }
            __builtin_amdgcn_s_barrier();
            __builtin_amdgcn_s_setprio(1);
            #pragma unroll
            for (int i = 0; i < 2; i++)
                #pragma unroll
                for (int j = 0; j < 2; j++)
                    #pragma unroll
                    for (int kk = 0; kk < 2; kk++)
                        acc[2*qm + i][2*qn + j] =
                            mfma16(af[i][kk], bff[j][kk], acc[2*qm + i][2*qn + j]);
            __builtin_amdgcn_s_setprio(0);
            if (q == 3){
                // ensure tile t+1 landed; keep tile t+2's 6 loads in flight
                if (st)              asm volatile("s_waitcnt vmcnt(6)" ::: "memory");
                else if (t + 1 < NT) asm volatile("s_waitcnt vmcnt(0)" ::: "memory");
            }
            __builtin_amdgcn_s_barrier();
            if (q == 3) __builtin_amdgcn_sched_barrier(0);
        }
        cb = cb + 1; if (cb >= 3) cb = 0;
    }
    #undef STAGE_A
    #undef STAGE_B

    #pragma unroll
    for (int mi = 0; mi < 4; mi++){
        #pragma unroll
        for (int ni = 0; ni < 4; ni++){
            int row0 = bm*256 + wm*64 + mi*16 + 4*g;
            int col  = bn*128 + wn*64 + ni*16 + r16;
            if (MODE == 0){
                u16* Cp = (u16*)C;
                #pragma unroll
                for (int rr = 0; rr < 4; rr++)
                    Cp[(u64)(row0+rr)*DM + col] = f2bf(acc[mi][ni][rr]);
            } else {
                float* Cp = (float*)C;
                float bv = bias[col];
                #pragma unroll
                for (int rr = 0; rr < 4; rr++)
                    Cp[(u64)(row0+rr)*DM + col] = acc[mi][ni][rr] + bv;
            }
        }
    }
}

// ---------------------------------------------------------------------------
// Vh [B*T][2048] -> Vt [B*H][128][T]  (Vt[bh][d][t] = Vh[b*T+t][h*128+d])
// ---------------------------------------------------------------------------
__global__ __launch_bounds__(256) void transpose_v(
    const u16* __restrict__ Vh, u16* __restrict__ Vt)
{
    __shared__ u16 tile[64*80];    // [t][d] 64x64 padded to 80
    int t0 = blockIdx.x*64, d0 = blockIdx.y*64, bh = blockIdx.z;
    int b = bh >> 4, h = bh & 15;
    int tid = threadIdx.x;
    #pragma unroll
    for (int rd = 0; rd < 2; rd++){
        int i = rd*256 + tid;
        int row = i >> 3, c = i & 7;
        u16x8 vv = *(const u16x8*)(Vh + (u64)(b*TT + t0 + row)*DM + h*DH + d0 + c*8);
        *(u16x8*)(tile + row*80 + c*8) = vv;
    }
    __syncthreads();
    #pragma unroll
    for (int rd = 0; rd < 2; rd++){
        int i = rd*256 + tid;
        int d = i >> 3, tc = (i & 7)*8;
        u16x8 vv;
        #pragma unroll
        for (int j = 0; j < 8; j++) vv[j] = tile[(tc + j)*80 + d];
        *(u16x8*)(Vt + (u64)(bh*DH + d0 + d)*TT + t0 + tc) = vv;
    }
}

// ---------------------------------------------------------------------------
// Flash attention fwd, 8-warp 32x32 swapped-QK^T structure (per guide §B).
// ---------------------------------------------------------------------------
static __device__ __forceinline__ void stage_kv(
    const u16* __restrict__ Kbase, const u16* __restrict__ Vbase,
    u16* ksh, u16* vsh, int tid)
{
    #pragma unroll
    for (int rd = 0; rd < 2; rd++){
        int ci = rd*512 + tid;
        int row = ci >> 4, ch = (ci & 15) ^ (row & 7);
        gload_lds16(Kbase + (u64)row*DM + ch*8, ksh + ci*8);
    }
    #pragma unroll
    for (int rd = 0; rd < 2; rd++){
        int ci = rd*512 + tid;
        int row = ci >> 3, ch = (ci & 7) ^ (row & 7);
        gload_lds16(Vbase + (u64)row*TT + ch*8, vsh + ci*8);
    }
}

__global__ __launch_bounds__(512, 2) void flash_attn2(
    const u16* __restrict__ Qh, const u16* __restrict__ Kh,
    const u16* __restrict__ Vt, u16* __restrict__ Ao)
{
    __shared__ __align__(16) u16 Ksh[2][64*128];
    __shared__ __align__(16) u16 Vsh[2][128*64];
    __shared__ __align__(16) float asc[8][32];

    const int f = blockIdx.x + 8*(blockIdx.y + 16*blockIdx.z);
    const int qt = f >> 5, bhl = f & 31;
    const int b = bhl >> 4, h = bhl & 15;
    const int bh = b*NH + h;

    const int tid = threadIdx.x, lane = tid & 63, wave = tid >> 6;
    const int l31 = lane & 31, hi = lane >> 5, l7 = lane & 7;
    const float scale = 0.08838834764831845f;   // 1/sqrt(128)

    bf16x8 qf[8];
    {
        const u16* qp = Qh + (u64)(b*TT + qt*256 + wave*32 + l31)*DM + h*DH + hi*8;
        #pragma unroll
        for (int c = 0; c < 8; c++) qf[c] = *(const bf16x8*)(qp + c*16);
    }

    const u16* Kb = Kh + (u64)(b*TT)*DM + h*DH;
    const u16* Vb = Vt + (u64)bh*DH*TT;

    f32x16 accO[4] = {};
    float m_ = -1e30f, l_ = 0.f;

    stage_kv(Kb, Vb, Ksh[0], Vsh[0], tid);
    __syncthreads();

    for (int it = 0; it < TT/64; it++){
        const int cur = it & 1;
        if (it < TT/64 - 1)
            stage_kv(Kb + (u64)(it+1)*64*DM, Vb + (it+1)*64,
                     Ksh[cur^1], Vsh[cur^1], tid);

        f32x16 s0 = {}, s1 = {};
        #pragma unroll
        for (int c = 0; c < 8; c++){
            int ch = (2*c + hi) ^ l7;
            bf16x8 k0 = *(const bf16x8*)(Ksh[cur] + l31*128 + ch*8);
            bf16x8 k1 = *(const bf16x8*)(Ksh[cur] + (32 + l31)*128 + ch*8);
            s0 = mfma32(k0, qf[c], s0);
            s1 = mfma32(k1, qf[c], s1);
        }

        float pe[32];
        #pragma unroll
        for (int r = 0; r < 16; r++){ pe[r] = s0[r]*scale; pe[16+r] = s1[r]*scale; }
        float mx = pe[0];
        #pragma unroll
        for (int i = 1; i < 32; i++) mx = fmaxf(mx, pe[i]);
        mx = fmaxf(mx, __shfl_xor(mx, 32));
        float mnew = fmaxf(m_, mx);
        float alpha = __expf(m_ - mnew);
        m_ = mnew;
        float ls = 0.f;
        #pragma unroll
        for (int i = 0; i < 32; i++){ pe[i] = __expf(pe[i] - mnew); ls += pe[i]; }
        ls += __shfl_xor(ls, 32);
        l_ = l_*alpha + ls;

        if (lane < 32) asc[wave][l31] = alpha;
        f32x4 av[4];
        #pragma unroll
        for (int j = 0; j < 4; j++) av[j] = *(const f32x4*)&asc[wave][8*j + 4*hi];
        #pragma unroll
        for (int dt = 0; dt < 4; dt++)
            #pragma unroll
            for (int r = 0; r < 16; r++)
                accO[dt][r] *= av[r>>2][r&3];

        bf16x8 pa[4];
        #pragma unroll
        for (int c = 0; c < 4; c++){
            u32 a0 = cvtpk(pe[8*c+0], pe[8*c+1]);
            u32 b0 = cvtpk(pe[8*c+4], pe[8*c+5]);
            u32 a1 = cvtpk(pe[8*c+2], pe[8*c+3]);
            u32 b1 = cvtpk(pe[8*c+6], pe[8*c+7]);
            asm volatile("v_permlane32_swap_b32 %0, %1" : "+v"(a0), "+v"(b0));
            asm volatile("v_permlane32_swap_b32 %0, %1" : "+v"(a1), "+v"(b1));
            u32x4 w = {a0, a1, b0, b1};
            pa[c] = __builtin_bit_cast(bf16x8, w);
        }

        #pragma unroll
        for (int dt = 0; dt < 4; dt++){
            #pragma unroll
            for (int c = 0; c < 4; c++){
                int ch = (2*c + hi) ^ l7;
                bf16x8 vf = *(const bf16x8*)(Vsh[cur] + (32*dt + l31)*64 + ch*8);
                accO[dt] = mfma32(pa[c], vf, accO[dt]);
            }
        }
        __syncthreads();
    }

    float linv = 1.f / l_;
    if (lane < 32) asc[wave][l31] = linv;
    f32x4 lv[4];
    #pragma unroll
    for (int j = 0; j < 4; j++) lv[j] = *(const f32x4*)&asc[wave][8*j + 4*hi];
    #pragma unroll
    for (int dt = 0; dt < 4; dt++){
        #pragma unroll
        for (int r = 0; r < 16; r++){
            int qrow = (r&3) + 8*(r>>2) + 4*hi;
            int grow = b*TT + qt*256 + wave*32 + qrow;
            int gcol = h*DH + 32*dt + l31;
            Ao[(u64)grow*DM + gcol] = f2bf(accO[dt][r] * lv[r>>2][r&3]);
        }
    }
}

// ---------------------------------------------------------------------------
extern "C" void kernel_launch(void* const* d_in, const int* in_sizes, int n_in,
                              void* d_out, int out_size, void* d_ws, size_t ws_size,
                              hipStream_t stream)
{
    const float* q  = (const float*)d_in[0];
    const float* k  = (const float*)d_in[1];
    const float* v  = (const float*)d_in[2];
    const float* wq = (const float*)d_in[3];
    const float* wk = (const float*)d_in[4];
    const float* wv = (const float*)d_in[5];
    const float* wo = (const float*)d_in[6];
    const float* bo = (const float*)d_in[7];
    float* out = (float*)d_out;

    const u64 SZQ = (u64)MT*DM;      // 8,388,608 elems
    const u64 SZW = (u64)DM*DM;      // 4,194,304 elems
    u16* ws  = (u16*)d_ws;
    u16* qb  = ws;                   // dead after projections -> reused as vt
    u16* kb  = ws + SZQ;             // dead after projections
    u16* vb  = ws + 2*SZQ;           // dead after projections -> reused as ao
    u16* wqb = ws + 3*SZQ;
    u16* wkb = wqb + SZW;
    u16* wvb = wqb + 2*SZW;
    u16* wob = wqb + 3*SZW;          // wqb..wob occupy 2*SZQ total
    u16* qh  = ws + 5*SZQ;
    u16* kh  = ws + 6*SZQ;
    u16* vh  = ws + 7*SZQ;
    u16* vt  = qb;                   // alias: qb dead after projections
    u16* ao  = vb;                   // alias: vb dead after projections
    // total footprint: 8*SZQ u16 = 134.2 MB

    cast_all<<<dim3(20480), dim3(256), 0, stream>>>(
        q, k, v, wq, wk, wv, wo, qb, kb, vb, wqb, wkb, wvb, wob);

    gemm8p<0><<<dim3(16, 16, 3), dim3(512), 0, stream>>>(
        qb, wqb, qh, kb, wkb, kh, vb, wvb, vh, nullptr);

    transpose_v<<<dim3(32, 2, 32), dim3(256), 0, stream>>>(vh, vt);

    flash_attn2<<<dim3(8, 16, 2), dim3(512), 0, stream>>>(qh, kh, vt, ao);

    gemm8p<1><<<dim3(16, 16, 1), dim3(512), 0, stream>>>(
        ao, wob, (void*)out, ao, wob, (void*)out, ao, wob, (void*)out, bo);
}